// Round 15
// baseline (379.346 us; speedup 1.0000x reference)
//
#include <hip/hip_runtime.h>
#include <hip/hip_cooperative_groups.h>
#include <cstdint>
#include <cstddef>

// AdMSoftmax loss, N=8192, D=256, S=1, M=0.4, unique-label branch.
//   G = x1 @ x2^T (fp8 MFMA, never materialized)
//   rownormsq_i = x1_i^T (X2^T X2) x1_i ; colnormsq_j = x2_j^T (X1^T X1) x2_j
//   rowExp_i = sum_j exp(G_ij/rn_i) ; colExp_j = sum_i exp(G_ij/cn_j) (fused epilogue)
//   L12_i = num - log(exp(num) + rowExp_i - exp(sim_ii)), num = sim_ii - 0.4
//   out = [loss, L12[8192], L21[8192]]
//
// R15: ONE cooperative persistent kernel. The ~105us non-gemmE residual has been
//      invariant across 5..9-node configs -> it's inter-dispatch overhead on a
//      serial chain; only removing dispatch boundaries kills it. Phases (R14
//      bodies, gridDim-stride virtual blocks): prep(2209v) -> syrk(1024v) ->
//      gemmN(512v) -> gemmE(4096v, R11-verbatim tile) -> final(32v) -> out[0],
//      grid.sync() between. Coherence: every cross-phase consumer is a
//      first-read-this-dispatch of write-through-stored or L2-atomic data -> no
//      stale-L1 hazard; replay staleness cleared at dispatch boundary; lossAcc
//      read agent-scope. LDS: one 33792B arena aliased per phase.

#define NROWS 8192
#define DIMK 256
#define MARGIN 0.4f
#define LOG2E 1.4426950408889634f
#define LN2 0.6931471805599453f

namespace cg = cooperative_groups;

typedef short short8 __attribute__((ext_vector_type(8)));
typedef float f32x4 __attribute__((ext_vector_type(4)));
typedef long longx2 __attribute__((ext_vector_type(2)));

__device__ __forceinline__ unsigned short f2bf(float f) {
  union { float f; unsigned u; } v; v.f = f;
  unsigned r = (v.u + 0x7fffu + ((v.u >> 16) & 1u)) >> 16;  // RNE
  return (unsigned short)r;
}

// fp32 -> OCP e4m3fn, RNE, saturate to 448
__device__ __forceinline__ unsigned char f2fp8(float f) {
  union { float f; unsigned u; } v; v.f = f;
  const unsigned s = (v.u >> 24) & 0x80u;
  const unsigned au = v.u & 0x7fffffffu;
  if (au >= 0x43e00000u) return (unsigned char)(s | 0x7eu);  // >=448 -> 448
  int e = (int)(au >> 23) - 127;
  if (e >= -6) {
    unsigned mfull = (au & 0x7fffffu) | 0x800000u;  // 24-bit 1.m
    unsigned r = (mfull + 0x7ffffu + ((mfull >> 20) & 1u)) >> 20;  // RNE to 4b (8..16)
    if (r == 16u) { r = 8u; ++e; }
    return (unsigned char)(s | ((unsigned)(e + 7) << 3) | (r & 7u));
  }
  float scaled = __builtin_fabsf(f) * 512.0f;  // subnormal: n * 2^-9
  unsigned n = (unsigned)(scaled + 0.5f);
  if (n >= 8u) return (unsigned char)(s | 0x08u);
  return (unsigned char)(s | n);
}

__device__ __forceinline__ void gl_lds16(const void* g, void* l) {
  __builtin_amdgcn_global_load_lds((const __attribute__((address_space(1))) void*)g,
                                   (__attribute__((address_space(3))) void*)l, 16, 0, 0);
}

__device__ __forceinline__ float fexp(float x) {
  return __builtin_amdgcn_exp2f(x * LOG2E);
}

__global__ __launch_bounds__(256)
void k_mega(const float* __restrict__ x1, const float* __restrict__ x2,
            unsigned short* __restrict__ Ab, unsigned short* __restrict__ Bb,
            unsigned char* __restrict__ A8, unsigned char* __restrict__ B8,
            float* __restrict__ zero_region,
            float* __restrict__ M1, float* __restrict__ M2,
            float* __restrict__ rowsq, float* __restrict__ colsq,
            float* __restrict__ rowExp, float* __restrict__ colExp,
            float* __restrict__ diag, double* __restrict__ lossAcc,
            float* __restrict__ out) {
  __shared__ __align__(16) char smem[33792];
  cg::grid_group gg = cg::this_grid();
  const int t = threadIdx.x;
  const int w = t >> 6, l = t & 63, quad = l >> 4, l15 = l & 15;

  // ======== phase 0: convert x -> bf16 + fp8 + diag dot | zero accumulators ====
  for (int v = blockIdx.x; v < 2209; v += gridDim.x) {
    if (v < 2048) {
      const int row = v * 4 + w;
      const float4 a = ((const float4*)(x1 + (size_t)row * DIMK))[l];
      const float4 b = ((const float4*)(x2 + (size_t)row * DIMK))[l];
      ushort4 ua, ub;
      ua.x = f2bf(a.x); ua.y = f2bf(a.y); ua.z = f2bf(a.z); ua.w = f2bf(a.w);
      ub.x = f2bf(b.x); ub.y = f2bf(b.y); ub.z = f2bf(b.z); ub.w = f2bf(b.w);
      ((ushort4*)(Ab + (size_t)row * DIMK))[l] = ua;
      ((ushort4*)(Bb + (size_t)row * DIMK))[l] = ub;
      uchar4 qa, qb;
      qa.x = f2fp8(a.x); qa.y = f2fp8(a.y); qa.z = f2fp8(a.z); qa.w = f2fp8(a.w);
      qb.x = f2fp8(b.x); qb.y = f2fp8(b.y); qb.z = f2fp8(b.z); qb.w = f2fp8(b.w);
      ((uchar4*)(A8 + (size_t)row * DIMK))[l] = qa;
      ((uchar4*)(B8 + (size_t)row * DIMK))[l] = qb;
      float d = a.x * b.x + a.y * b.y + a.z * b.z + a.w * b.w;
#pragma unroll
      for (int m = 1; m < 64; m <<= 1) d += __shfl_xor(d, m);
      if (l == 0) diag[row] = d;
    } else {
      const size_t off = (size_t)(v - 2048) * 1024 + t * 4;  // float units
      float4 z = {0.f, 0.f, 0.f, 0.f};
      *(float4*)(zero_region + off) = z;
    }
  }
  gg.sync();

  // ======== phase 1: M = X^T X, 64x64 tiles, 32 K-segs of 256 (1024 virtual) ====
  {
    unsigned short* AsS = (unsigned short*)smem;             // 64*32 ushort = 4K
    unsigned short* BsS = (unsigned short*)(smem + 8192);
    const int wrS = (w >> 1) * 32, wcS = (w & 1) * 32;
    const int nn = t & 31, c0 = (t >> 5) * 8;
    for (int v = blockIdx.x; v < 1024; v += gridDim.x) {
      __syncthreads();
      const int bxS = v & 3, byS = (v >> 2) & 3, bzS = v >> 4;
      const int mat = bzS & 1, kseg = bzS >> 1;
      const unsigned short* X = mat ? Bb : Ab;
      float* Mo = mat ? M2 : M1;
      const int a0 = byS * 64, b0 = bxS * 64;
      f32x4 acc[2][2] = {};
      const int nb = kseg * 256;
      for (int n0 = nb; n0 < nb + 256; n0 += 32) {
        short8 va = *(const short8*)(X + (size_t)(n0 + nn) * DIMK + a0 + c0);
        short8 vb = *(const short8*)(X + (size_t)(n0 + nn) * DIMK + b0 + c0);
#pragma unroll
        for (int i = 0; i < 8; ++i) {
          const int c = c0 + i;
          const int sl = (((nn >> 3) ^ ((c >> 1) & 3)) << 3) + (nn & 7);
          AsS[c * 32 + sl] = va[i];
          BsS[c * 32 + sl] = vb[i];
        }
        __syncthreads();
        short8 af[2], bg[2];
#pragma unroll
        for (int i = 0; i < 2; ++i) {
          const int ra = wrS + i * 16 + l15;
          af[i] = *(const short8*)&AsS[ra * 32 + ((quad ^ ((ra >> 1) & 3)) << 3)];
          const int rb = wcS + i * 16 + l15;
          bg[i] = *(const short8*)&BsS[rb * 32 + ((quad ^ ((rb >> 1) & 3)) << 3)];
        }
#pragma unroll
        for (int i = 0; i < 2; ++i)
#pragma unroll
          for (int j = 0; j < 2; ++j)
            acc[i][j] = __builtin_amdgcn_mfma_f32_16x16x32_bf16(af[i], bg[j], acc[i][j], 0, 0, 0);
        __syncthreads();
      }
#pragma unroll
      for (int i = 0; i < 2; ++i)
#pragma unroll
        for (int j = 0; j < 2; ++j)
#pragma unroll
          for (int r = 0; r < 4; ++r) {
            const int lr = wrS + i * 16 + quad * 4 + r;
            const int lc = wcS + j * 16 + l15;
            atomicAdd(&Mo[(size_t)(a0 + lr) * 256 + b0 + lc], acc[i][j][r]);
          }
    }
  }
  gg.sync();

  // ======== phase 2: norm GEMM Y=X*M + dot epilogue (512 virtual, K-split x2) ====
  {
    unsigned short* AsN = (unsigned short*)smem;             // [2][4096]
    unsigned short* BsN = (unsigned short*)(smem + 16384);   // [2][4096]
    const int wrN = (w >> 1) * 64, wcN = (w & 1) * 64;
    const int sr0 = l >> 2, slot = l & 3;
    for (int v = blockIdx.x; v < 512; v += gridDim.x) {
      __syncthreads();
      const int bxN = v & 63, byN = (v >> 6) & 1, bzN = v >> 7;
      const unsigned short* A;
      const float* Mf;
      const float* Xf;
      float* sq;
      if ((bzN & 1) == 0) { A = Ab; Mf = M2; Xf = x1; sq = rowsq; }
      else                { A = Bb; Mf = M1; Xf = x2; sq = colsq; }
      const int kbase = (bzN >> 1) * 128;
      const int row0 = bxN * 128;
      const int col0 = byN * 128;
      f32x4 acc[4][4] = {};

      const int cA = w * 2, cB = w * 2 + 1;
      const int rA = cA * 16 + sr0, rB = cB * 16 + sr0;
      const int scA = (slot ^ ((rA >> 1) & 3)) << 3;
      const int scB = (slot ^ ((rB >> 1) & 3)) << 3;
      const unsigned short* pA0 = A + (size_t)(row0 + rA) * DIMK + kbase + scA;
      const unsigned short* pA1 = A + (size_t)(row0 + rB) * DIMK + kbase + scB;
      const int dA0 = cA * 512 + l * 8, dA1 = cB * 512 + l * 8;

      auto stageB = [&](int k0, int buf) {
#pragma unroll
        for (int g = 0; g < 2; ++g) {
          const int e = g * 2048 + t * 8;
          const int c = e >> 5, kk = e & 31;
          const float4 v0 = *(const float4*)(Mf + (size_t)(col0 + c) * 256 + kbase + k0 + kk);
          const float4 v1 = *(const float4*)(Mf + (size_t)(col0 + c) * 256 + kbase + k0 + kk + 4);
          ushort4 u0, u1;
          u0.x = f2bf(v0.x); u0.y = f2bf(v0.y); u0.z = f2bf(v0.z); u0.w = f2bf(v0.w);
          u1.x = f2bf(v1.x); u1.y = f2bf(v1.y); u1.z = f2bf(v1.z); u1.w = f2bf(v1.w);
          const int sw = ((kk >> 3) ^ ((c >> 1) & 3)) << 3;
          *(ushort4*)&BsN[buf * 4096 + c * 32 + sw] = u0;
          *(ushort4*)&BsN[buf * 4096 + c * 32 + sw + 4] = u1;
        }
      };
      auto issueA = [&](int k0, int buf) {
        gl_lds16(pA0 + k0, &AsN[buf * 4096 + dA0]);
        gl_lds16(pA1 + k0, &AsN[buf * 4096 + dA1]);
      };

      stageB(0, 0);
      issueA(0, 0);
#pragma unroll
      for (int k = 0; k < 4; ++k) {
        const int cur = k & 1;
        __syncthreads();
        if (k < 3) { stageB((k + 1) * 32, cur ^ 1); issueA((k + 1) * 32, cur ^ 1); }
        short8 af[4], bg[4];
#pragma unroll
        for (int i = 0; i < 4; ++i) {
          const int ra = wrN + i * 16 + l15;
          af[i] = *(const short8*)&AsN[cur * 4096 + ra * 32 + ((quad ^ ((ra >> 1) & 3)) << 3)];
          const int rb = wcN + i * 16 + l15;
          bg[i] = *(const short8*)&BsN[cur * 4096 + rb * 32 + ((quad ^ ((rb >> 1) & 3)) << 3)];
        }
#pragma unroll
        for (int i = 0; i < 4; ++i)
#pragma unroll
          for (int j = 0; j < 4; ++j)
            acc[i][j] = __builtin_amdgcn_mfma_f32_16x16x32_bf16(af[i], bg[j], acc[i][j], 0, 0, 0);
      }

#pragma unroll
      for (int i = 0; i < 4; ++i) {
#pragma unroll
        for (int r = 0; r < 4; ++r) {
          const int lr = wrN + i * 16 + quad * 4 + r;
          const float* xr = Xf + (size_t)(row0 + lr) * DIMK + col0 + wcN;
          float rp = 0.f;
#pragma unroll
          for (int j = 0; j < 4; ++j) rp += acc[i][j][r] * xr[j * 16 + l15];
          rp += __shfl_xor(rp, 1); rp += __shfl_xor(rp, 2);
          rp += __shfl_xor(rp, 4); rp += __shfl_xor(rp, 8);
          if (l15 == 0) atomicAdd(&sq[row0 + lr], rp);
        }
      }
    }
  }
  gg.sync();

  // ======== phase 3: main GEMM + exp epilogue (4096 virtual, R11 tile body) ====
  {
    unsigned char* AsE = (unsigned char*)smem;               // [2][8192]
    unsigned char* BsE = (unsigned char*)(smem + 16384);     // [2][8192]
    float* cRow = (float*)(smem + 32768);                    // 128 f32
    float* cCol = (float*)(smem + 33280);                    // 128 f32
    const int wrE = (w >> 1) * 64, wcE = (w & 1) * 64;
    const int srow = t >> 2;
    const int cl = (t & 3) ^ ((t >> 3) & 3);
    const int d0 = t * 16, d1 = 4096 + t * 16;
    for (int v = blockIdx.x; v < 4096; v += gridDim.x) {
      __syncthreads();  // prior tile's LDS/scale reads fully done
      const int row0 = (v & 63) * 128;
      const int col0 = (v >> 6) * 128;
      if (t < 128) cRow[t] = LOG2E * rsqrtf(rowsq[row0 + t]);
      else cCol[t - 128] = LOG2E * rsqrtf(colsq[col0 + t - 128]);

      f32x4 acc[4][4] = {};
      const unsigned char* gA0 = A8 + (size_t)(row0 + srow) * DIMK + cl * 16;
      const unsigned char* gA1 = A8 + (size_t)(row0 + 64 + srow) * DIMK + cl * 16;
      const unsigned char* gB0 = B8 + (size_t)(col0 + srow) * DIMK + cl * 16;
      const unsigned char* gB1 = B8 + (size_t)(col0 + 64 + srow) * DIMK + cl * 16;

      auto issue = [&](int k0, int buf) {
        gl_lds16(gA0 + k0, &AsE[buf * 8192 + d0]);
        gl_lds16(gA1 + k0, &AsE[buf * 8192 + d1]);
        gl_lds16(gB0 + k0, &BsE[buf * 8192 + d0]);
        gl_lds16(gB1 + k0, &BsE[buf * 8192 + d1]);
      };

      issue(0, 0);
#pragma unroll
      for (int it = 0; it < 4; ++it) {
        const int cur = it & 1;
        __syncthreads();
        if (it < 3) issue((it + 1) * 64, cur ^ 1);
        longx2 av[4], bv[4];
#pragma unroll
        for (int i = 0; i < 4; ++i) {
          const int ra = wrE + i * 16 + l15;
          const int pcA = quad ^ ((ra >> 1) & 3);
          av[i] = *(const longx2*)&AsE[cur * 8192 + ra * 64 + pcA * 16];
          const int rb = wcE + i * 16 + l15;
          const int pcB = quad ^ ((rb >> 1) & 3);
          bv[i] = *(const longx2*)&BsE[cur * 8192 + rb * 64 + pcB * 16];
        }
#pragma unroll
        for (int kc = 0; kc < 2; ++kc)
#pragma unroll
          for (int i = 0; i < 4; ++i)
#pragma unroll
            for (int j = 0; j < 4; ++j)
              acc[i][j] = __builtin_amdgcn_mfma_f32_16x16x32_fp8_fp8(av[i][kc], bv[j][kc],
                                                                     acc[i][j], 0, 0, 0);
      }

      // exp epilogue. C/D: row_local = wrE+i*16+quad*4+r ; col_local = wcE+j*16+l15
      float cj[4];
#pragma unroll
      for (int j = 0; j < 4; ++j) cj[j] = cCol[wcE + j * 16 + l15];
      float colpart[4] = {0.f, 0.f, 0.f, 0.f};
#pragma unroll
      for (int i = 0; i < 4; ++i) {
#pragma unroll
        for (int r = 0; r < 4; ++r) {
          const int lr = wrE + i * 16 + quad * 4 + r;
          const float ci = cRow[lr];
          float rp = 0.f;
#pragma unroll
          for (int j = 0; j < 4; ++j) {
            const float g = acc[i][j][r];
            rp += __builtin_amdgcn_exp2f(g * ci);
            colpart[j] += __builtin_amdgcn_exp2f(g * cj[j]);
          }
          rp += __shfl_xor(rp, 1); rp += __shfl_xor(rp, 2);
          rp += __shfl_xor(rp, 4); rp += __shfl_xor(rp, 8);
          if (l15 == 0) atomicAdd(&rowExp[row0 + lr], rp);
        }
      }
#pragma unroll
      for (int j = 0; j < 4; ++j) {
        float cp = colpart[j];
        cp += __shfl_xor(cp, 16); cp += __shfl_xor(cp, 32);
        if (l < 16) atomicAdd(&colExp[col0 + wcE + j * 16 + l15], cp);
      }
    }
  }
  gg.sync();

  // ======== phase 4: finalize (32 virtual of 256 elems) + loss ====
  {
    double part = 0.0;
    for (int v = blockIdx.x; v < 32; v += gridDim.x) {
      const int i = v * 256 + t;
      const float d = diag[i];
      const float s1 = d * rsqrtf(rowsq[i]);
      const float s2 = d * rsqrtf(colsq[i]);
      const float n1 = s1 - MARGIN, n2 = s2 - MARGIN;
      const float L1 = n1 - LN2 * __builtin_amdgcn_logf(rowExp[i] - fexp(s1) + fexp(n1));
      const float L2 = n2 - LN2 * __builtin_amdgcn_logf(colExp[i] - fexp(s2) + fexp(n2));
      out[1 + i] = L1;
      out[1 + NROWS + i] = L2;
      part += (double)L1 + (double)L2;
    }
#pragma unroll
    for (int m = 1; m < 64; m <<= 1) part += __shfl_xor(part, m);
    double* red = (double*)smem;
    __syncthreads();
    if (l == 0) red[w] = part;
    __syncthreads();
    if (t == 0) {
      const double s = red[0] + red[1] + red[2] + red[3];
      if (s != 0.0) atomicAdd(lossAcc, s);
    }
  }
  gg.sync();
  if (blockIdx.x == 0 && t == 0) {
    const double la = __hip_atomic_load(lossAcc, __ATOMIC_RELAXED, __HIP_MEMORY_SCOPE_AGENT);
    out[0] = (float)(-la / (double)NROWS);
  }
}

extern "C" void kernel_launch(void* const* d_in, const int* in_sizes, int n_in,
                              void* d_out, int out_size, void* d_ws, size_t ws_size,
                              hipStream_t stream) {
  const float* x1 = (const float*)d_in[0];
  const float* x2 = (const float*)d_in[1];
  float* out = (float*)d_out;
  char* ws = (char*)d_ws;

  unsigned short* Ab = (unsigned short*)(ws);            // 4 MB  x1 bf16
  unsigned short* Bb = (unsigned short*)(ws + 4194304);  // 4 MB  x2 bf16
  // zero region: 8388608 .. +659456 (161 blocks x 4096 B) covers M1..ctrl
  float* zr = (float*)(ws + 8388608);
  float* M1 = (float*)(ws + 8388608);      // 256 KB  X1^T X1 (fp32 acc)
  float* M2 = (float*)(ws + 8650752);      // 256 KB  X2^T X2
  float* rowsq = (float*)(ws + 8912896);   // 32 KB
  float* colsq = (float*)(ws + 8945664);   // 32 KB
  float* rowExp = (float*)(ws + 8978432);  // 32 KB
  float* colExp = (float*)(ws + 9011200);  // 32 KB
  char* ctrl = ws + 9043968;               // 4 KB control page (zeroed)
  double* lossAcc = (double*)(ctrl);
  float* diag = (float*)(ws + 9048064);    // 32 KB (not zeroed)
  unsigned char* A8 = (unsigned char*)(ws + 9080832);   // 2 MB  x1 fp8
  unsigned char* B8 = (unsigned char*)(ws + 11177984);  // 2 MB  x2 fp8

  int maxB = 0;
  hipOccupancyMaxActiveBlocksPerMultiprocessor(&maxB, k_mega, 256, 0);
  if (maxB < 1) maxB = 1;
  unsigned grid = (unsigned)maxB * 256u;   // 256 CUs on MI355X
  if (grid > 4096u) grid = 4096u;

  void* args[] = {(void*)&x1, (void*)&x2, (void*)&Ab, (void*)&Bb,
                  (void*)&A8, (void*)&B8, (void*)&zr, (void*)&M1, (void*)&M2,
                  (void*)&rowsq, (void*)&colsq, (void*)&rowExp, (void*)&colExp,
                  (void*)&diag, (void*)&lossAcc, (void*)&out};
  hipLaunchCooperativeKernel((void*)k_mega, dim3(grid), dim3(256), args, 0, stream);
}